// Round 1
// baseline (50.172 us; speedup 1.0000x reference)
//
#include <hip/hip_runtime.h>

// MatryoshkaHarmonicMixing: out[b,s,d] = x[b,s,d]
//   + (d in [512,1024) && d%2==0) * s1 * x[b,s,d/2]
//   + (d in [512,2048) && d%4==0) * s2 * x[b,s,d/4]
//   + (d in [512,2048) && d%8==0) * s3 * x[b,s,d/8]
// where s_o = sigmoid(weights[o-1]).  D_MODEL=2048, MIN_CUTOFF=512.

#define D_MODEL 2048

__global__ __launch_bounds__(256) void mhm_kernel(
    const float* __restrict__ x,
    const float* __restrict__ w,
    float* __restrict__ out,
    long long n4)
{
    const float s1 = 1.0f / (1.0f + expf(-w[0]));
    const float s2 = 1.0f / (1.0f + expf(-w[1]));
    const float s3 = 1.0f / (1.0f + expf(-w[2]));

    const long long stride = (long long)gridDim.x * blockDim.x;
    for (long long i = (long long)blockIdx.x * blockDim.x + threadIdx.x;
         i < n4; i += stride) {
        const long long e0 = i << 2;                 // first element of this float4
        const int d0 = (int)(e0 & (D_MODEL - 1));    // position within the row
        const long long row = e0 - d0;               // row start (flat)

        float4 v = reinterpret_cast<const float4*>(x)[i];

        if (d0 >= 512) {
            // octave 1 (stride 2): tgt even, tgt in [512,1024)
            if (d0 < 1024) {
                v.x += s1 * x[row + (d0 >> 1)];
                v.z += s1 * x[row + (d0 >> 1) + 1];
            }
            // octave 2 (stride 4): tgt % 4 == 0 -> only d0 itself
            v.x += s2 * x[row + (d0 >> 2)];
            // octave 3 (stride 8): tgt % 8 == 0
            if ((d0 & 7) == 0) {
                v.x += s3 * x[row + (d0 >> 3)];
            }
        }

        reinterpret_cast<float4*>(out)[i] = v;
    }
}

extern "C" void kernel_launch(void* const* d_in, const int* in_sizes, int n_in,
                              void* d_out, int out_size, void* d_ws, size_t ws_size,
                              hipStream_t stream) {
    const float* x = (const float*)d_in[0];     // (4, 4096, 2048) f32
    const float* w = (const float*)d_in[1];     // (3,) f32
    float* out = (float*)d_out;

    const long long n = (long long)out_size;    // 4*4096*2048
    const long long n4 = n >> 2;                // float4 count

    const int threads = 256;
    int blocks = 2048;                          // grid-stride, ~8 blocks/CU
    long long needed = (n4 + threads - 1) / threads;
    if (needed < blocks) blocks = (int)needed;

    mhm_kernel<<<blocks, threads, 0, stream>>>(x, w, out, n4);
}